// Round 3
// baseline (429.933 us; speedup 1.0000x reference)
//
#include <hip/hip_runtime.h>
#include <math.h>

// GaussianLayer: per row (B=524288): mu=x[0], sigma=exp(0.5*x[1]);
// pdf over xx=-99..99, cumsum over 199 bins. Output (B,199) fp32 = 417 MB.
//
// Accounting: dur_us includes the harness ~264 us / 1.67 GB poison fill.
// Kernel-proper ~150 us vs 67 us at the fill's own 6.26 TB/s write rate.
//
// Falsified so far: write-allocate fetch (R6 nt null; fill writes FETCH~0
// with plain dwordx4), L2-bypass stores (R7: poison dirty lines in L2
// evict after HBM-direct writes -> NaN), inter-block stall / store-drain
// serialization (R8 persistent pipelined blocks: null).
//
// R9: the one structure R6/R8 share is the barrier-coupled LDS transpose:
// 4-wave blocks convoyed by 2 barriers per 25 KB tile, stores in short
// block-synchronized bursts. The fill saturates HBM with wave-AUTONOMOUS
// streams at 3 waves/CU. This version deletes LDS and barriers entirely:
//   lane l computes bins 4l..4l+3 of a row (serial cumsum in-lane),
//   one 6-step __shfl_up scan over lane sums -> exclusive prefix,
//   store 16B/lane (lanes 0..48) + 3-float tail (lane 49).
//   Each wave owns 64 CONSECUTIVE rows = 50,944 B contiguous stream;
//   row params loaded once per wave (x[rowBase+l], lane-distributed),
//   broadcast per row via readlane. No __shared__, no __syncthreads.
// pdf fused into a single exp2: p = exp2(ca*t^2 + li),
//   li = log2(inv_norm) = -1.32574806 - log2e/2 * x1  (no log needed).

#define NT  256
#define RPW 64            // consecutive rows per wave

__device__ __forceinline__ float bcast(float v, int lane) {
    return __int_as_float(__builtin_amdgcn_readlane(__float_as_int(v), lane));
}

__global__ __launch_bounds__(NT, 4)
void gauss_cdf_kernel(const float2* __restrict__ x, float* __restrict__ out, int B) {
    const int l = threadIdx.x & 63;
    const int w = (blockIdx.x * NT + threadIdx.x) >> 6;   // global wave id
    const int rowBase = w * RPW;
    if (rowBase >= B) return;

    // 64 rows' params, lane-distributed (1 coalesced 512B load per wave)
    float2 vx = x[min(rowBase + l, B - 1)];

    const float bl   = 4.0f * (float)l - 99.0f;  // first bin center - 99 offset
    const bool  full = (l <= 48);                // 4 valid bins
    const bool  any  = (l <= 49);                // lane 49: 3 valid bins

    const int rmax = min(RPW, B - rowBase);
    #pragma unroll 2
    for (int i = 0; i < rmax; ++i) {
        const float mu   = bcast(vx.x, i);
        const float lsig = bcast(vx.y, i);
        // -log2e/2 = -0.72134752; log2(1/sqrt(2pi)) = -1.32574806
        const float li = -1.3257480647361593f - 0.7213475204444817f * lsig;
        const float s  = __builtin_amdgcn_exp2f(-0.7213475204444817f * lsig); // 1/sigma
        const float ca = -0.7213475204444817f * s * s;   // -log2e/(2 sigma^2)

        const float t0 = bl - mu, t1 = t0 + 1.f, t2 = t0 + 2.f, t3 = t0 + 3.f;
        float p0 = __builtin_amdgcn_exp2f(__builtin_fmaf(ca, t0 * t0, li));
        float p1 = __builtin_amdgcn_exp2f(__builtin_fmaf(ca, t1 * t1, li));
        float p2 = __builtin_amdgcn_exp2f(__builtin_fmaf(ca, t2 * t2, li));
        float p3 = __builtin_amdgcn_exp2f(__builtin_fmaf(ca, t3 * t3, li));
        if (!any)  { p0 = 0.f; p1 = 0.f; p2 = 0.f; }   // lanes 50..63: no bins
        if (!full) { p3 = 0.f; }                        // lane 49: bin 199 absent

        // in-lane serial cumsum of 4 bins
        const float c0 = p0, c1 = c0 + p1, c2 = c1 + p2, c3 = c2 + p3;

        // inclusive wave scan of lane sums (6 shuffle steps)
        float sc = c3;
        #pragma unroll
        for (int d = 1; d < 64; d <<= 1) {
            float t = __shfl_up(sc, d, 64);
            if (l >= d) sc += t;
        }
        const float e = sc - c3;   // exclusive prefix of earlier lanes

        const float o0 = e + c0, o1 = e + c1, o2 = e + c2, o3 = e + c3;
        float* ro = out + (size_t)(rowBase + i) * 199;
        if (full) {
            // bytes [796r + 16l, +16): 4B-aligned (75% of rows not 16B-aligned);
            // memcpy = correct under any lowering (dwordx4-unaligned or split)
            float o4[4] = {o0, o1, o2, o3};
            __builtin_memcpy(ro + 4 * l, o4, 16);
        } else if (l == 49) {
            ro[196] = o0; ro[197] = o1; ro[198] = o2;
        }
    }
}

extern "C" void kernel_launch(void* const* d_in, const int* in_sizes, int n_in,
                              void* d_out, int out_size, void* d_ws, size_t ws_size,
                              hipStream_t stream) {
    const float2* x = (const float2*)d_in[0];
    float* out = (float*)d_out;
    const int B = in_sizes[0] / 2;                    // (B,2) fp32
    const int waves = (B + RPW - 1) / RPW;            // 8192
    const int grid  = (waves + (NT / 64) - 1) / (NT / 64);   // 2048 blocks
    gauss_cdf_kernel<<<grid, NT, 0, stream>>>(x, out, B);
}